// Round 1
// baseline (199.799 us; speedup 1.0000x reference)
//
#include <hip/hip_runtime.h>

typedef unsigned short u16;
typedef __attribute__((ext_vector_type(8))) short short8;
typedef __attribute__((ext_vector_type(4))) float floatx4;
typedef __attribute__((ext_vector_type(4))) unsigned short ushortx4;

#define BM 128
#define BN 128
#define BK 32

// dims
#define BATCH 4
#define SEQ   2048
#define DMODEL 1024

__device__ __forceinline__ u16 f2bf(float f) {
  unsigned int u = __builtin_bit_cast(unsigned int, f);
  u = (u + 0x7FFFu + ((u >> 16) & 1u)) >> 16;
  return (u16)u;
}

typedef const __attribute__((address_space(1))) unsigned int as1_u32;
typedef __attribute__((address_space(3))) unsigned int as3_u32;

__device__ __forceinline__ void gload16(const void* gp, void* lp) {
  __builtin_amdgcn_global_load_lds((as1_u32*)gp, (as3_u32*)lp, 16, 0, 0);
}

// ---------------------------------------------------------------------------
// Core: C[128x128] tile of A[M][K] @ Bt[N][K]^T, bf16 inputs, fp32 acc.
// 256 threads = 4 waves in 2x2, each wave 64x64 = 4x4 frags of 16x16x32 MFMA.
// Single-buffer LDS, global_load_lds width-16 staging (m97 structure).
// ---------------------------------------------------------------------------
__device__ __forceinline__ void gemm_tile_bt(
    const u16* __restrict__ A, int lda,
    const u16* __restrict__ B, int ldb,
    int m0, int n0, int kEnd,
    u16* As, u16* Bs, floatx4 acc[4][4])
{
  const int tid  = threadIdx.x;
  const int wave = tid >> 6;
  const int lane = tid & 63;
  const int wr = wave >> 1, wc = wave & 1;
  const int r16 = lane & 15;
  const int kk  = (lane >> 4) * 8;
  const int srow = lane >> 2;        // 0..15
  const int scol = (lane & 3) * 8;   // 0,8,16,24

  const u16* gA = A + (size_t)(m0 + 32*wave + srow) * lda + scol;
  const u16* gB = B + (size_t)(n0 + 32*wave + srow) * ldb + scol;
  u16* lA = As + (32*wave)*BK;
  u16* lB = Bs + (32*wave)*BK;

  for (int k0 = 0; k0 < kEnd; k0 += BK) {
    gload16(gA + k0, lA);
    gload16(gA + (size_t)16*lda + k0, lA + 16*BK);
    gload16(gB + k0, lB);
    gload16(gB + (size_t)16*ldb + k0, lB + 16*BK);
    __syncthreads();
    short8 af[4], bfr[4];
    #pragma unroll
    for (int m = 0; m < 4; ++m)
      af[m] = *(const short8*)(As + (wr*64 + m*16 + r16)*BK + kk);
    #pragma unroll
    for (int n = 0; n < 4; ++n)
      bfr[n] = *(const short8*)(Bs + (wc*64 + n*16 + r16)*BK + kk);
    #pragma unroll
    for (int m = 0; m < 4; ++m)
      #pragma unroll
      for (int n = 0; n < 4; ++n)
        acc[m][n] = __builtin_amdgcn_mfma_f32_16x16x32_bf16(af[m], bfr[n], acc[m][n], 0, 0, 0);
    __syncthreads();
  }
}

// ---------------------------------------------------------------------------
// 1) fp32 -> bf16 convert: X (8192x1024) -> Xb ; W_Q/W_K/W_V -> Wb[3][1024][1024]
// ---------------------------------------------------------------------------
__global__ __launch_bounds__(256)
void convert_k(const float* __restrict__ X,
               const float* __restrict__ WQ,
               const float* __restrict__ WK,
               const float* __restrict__ WV,
               u16* __restrict__ Xb, u16* __restrict__ Wb)
{
  const int NX = (BATCH*SEQ*DMODEL) / 4;   // float4 units: 2,097,152
  const int NW = (DMODEL*DMODEL) / 4;      // 262,144
  const int total = NX + 3*NW;
  for (int i = blockIdx.x * 256 + threadIdx.x; i < total; i += gridDim.x * 256) {
    const float4* src; u16* dst; int j;
    if (i < NX) { src = (const float4*)X; j = i; dst = Xb; }
    else {
      int t = i - NX; int w = t / NW; j = t - w * NW;
      src = (const float4*)(w == 0 ? WQ : (w == 1 ? WK : WV));
      dst = Wb + (size_t)w * (DMODEL*DMODEL);
    }
    float4 v = src[j];
    ushortx4 p = { f2bf(v.x), f2bf(v.y), f2bf(v.z), f2bf(v.w) };
    *(ushortx4*)(dst + (size_t)j * 4) = p;
  }
}

// ---------------------------------------------------------------------------
// 2) QKV projection: out = Xb @ W^T.  VT=false: z in {0,1} -> Q,K row-major bf16.
//    VT=true: V, written batch-transposed Vt[b][d][s].
// ---------------------------------------------------------------------------
template<bool VT>
__global__ __launch_bounds__(256)
void qkv_gemm(const u16* __restrict__ Xb, const u16* __restrict__ Wb,
              u16* __restrict__ Q, u16* __restrict__ K, u16* __restrict__ Vt)
{
  __shared__ u16 As[BM*BK];
  __shared__ u16 Bs[BN*BK];
  const int m0 = blockIdx.x * BM;
  const int n0 = blockIdx.y * BN;
  const int z  = VT ? 2 : blockIdx.z;
  const u16* W = Wb + (size_t)z * (DMODEL*DMODEL);

  floatx4 acc[4][4] = {};
  gemm_tile_bt(Xb, DMODEL, W, DMODEL, m0, n0, DMODEL, As, Bs, acc);

  const int lane = threadIdx.x & 63, wave = threadIdx.x >> 6;
  const int wr = wave >> 1, wc = wave & 1;
  const int row0 = m0 + wr*64 + (lane >> 4) * 4;
  const int col0 = n0 + wc*64 + (lane & 15);

  if (!VT) {
    u16* O = (z == 0) ? Q : K;
    #pragma unroll
    for (int m = 0; m < 4; ++m)
      #pragma unroll
      for (int n = 0; n < 4; ++n) {
        int col = col0 + n*16;
        #pragma unroll
        for (int i = 0; i < 4; ++i)
          O[(size_t)(row0 + m*16 + i) * DMODEL + col] = f2bf(acc[m][n][i]);
      }
  } else {
    #pragma unroll
    for (int m = 0; m < 4; ++m) {
      int gm = row0 + m*16;
      int b = gm >> 11, s = gm & (SEQ - 1);
      #pragma unroll
      for (int n = 0; n < 4; ++n) {
        int d = col0 + n*16;
        ushortx4 p = { f2bf(acc[m][n][0]), f2bf(acc[m][n][1]),
                       f2bf(acc[m][n][2]), f2bf(acc[m][n][3]) };
        *(ushortx4*)(Vt + ((size_t)b * DMODEL + d) * SEQ + s) = p;
      }
    }
  }
}

// ---------------------------------------------------------------------------
// 3) scores = Q @ K^T / 32, lower-triangular tiles only, fp32 out
// ---------------------------------------------------------------------------
__global__ __launch_bounds__(256)
void scores_gemm(const u16* __restrict__ Qb, const u16* __restrict__ Kb,
                 float* __restrict__ Sc)
{
  __shared__ u16 As[BM*BK];
  __shared__ u16 Bs[BN*BK];
  const int b = blockIdx.y;
  const int t = blockIdx.x;             // 0..135 triangular
  int qt = 0;
  while ((qt + 1) * (qt + 2) / 2 <= t) ++qt;
  const int kt = t - qt * (qt + 1) / 2;

  const u16* Q = Qb + (size_t)b * SEQ * DMODEL;
  const u16* K = Kb + (size_t)b * SEQ * DMODEL;

  floatx4 acc[4][4] = {};
  gemm_tile_bt(Q, DMODEL, K, DMODEL, qt * BM, kt * BN, DMODEL, As, Bs, acc);

  float* S = Sc + (size_t)b * SEQ * SEQ;
  const int lane = threadIdx.x & 63, wave = threadIdx.x >> 6;
  const int wr = wave >> 1, wc = wave & 1;
  const int row0 = qt*BM + wr*64 + (lane >> 4) * 4;
  const int col0 = kt*BN + wc*64 + (lane & 15);
  #pragma unroll
  for (int m = 0; m < 4; ++m)
    #pragma unroll
    for (int n = 0; n < 4; ++n) {
      int col = col0 + n*16;
      #pragma unroll
      for (int i = 0; i < 4; ++i)
        S[(size_t)(row0 + m*16 + i) * SEQ + col] = acc[m][n][i] * 0.03125f;
    }
}

// ---------------------------------------------------------------------------
// 4) causal row softmax, in-place: fp32 row -> bf16 P overlaid at row start
//    (P element k at u16 index k; row slot stride stays 8KB = 4096 u16)
// ---------------------------------------------------------------------------
__global__ __launch_bounds__(256)
void softmax_k(float* __restrict__ Sc)
{
  __shared__ float buf[SEQ];
  __shared__ float red[4];
  const int rg = blockIdx.x;           // 0..8191
  const int q = rg & (SEQ - 1);
  float* row = Sc + (size_t)rg * SEQ;
  u16* prow = (u16*)row;
  const int tid = threadIdx.x;
  const int lane = tid & 63, wave = tid >> 6;
  const int n = q + 1;

  float lmax = -3.4e38f;
  for (int k = tid; k < n; k += 256) {
    float v = row[k];
    buf[k] = v;
    lmax = fmaxf(lmax, v);
  }
  #pragma unroll
  for (int off = 32; off >= 1; off >>= 1)
    lmax = fmaxf(lmax, __shfl_xor(lmax, off));
  if (lane == 0) red[wave] = lmax;
  __syncthreads();
  const float rmax = fmaxf(fmaxf(red[0], red[1]), fmaxf(red[2], red[3]));
  __syncthreads();

  float lsum = 0.f;
  for (int k = tid; k < n; k += 256) {
    float e = __expf(buf[k] - rmax);
    buf[k] = e;
    lsum += e;
  }
  #pragma unroll
  for (int off = 32; off >= 1; off >>= 1)
    lsum += __shfl_xor(lsum, off);
  if (lane == 0) red[wave] = lsum;
  __syncthreads();
  const float inv = 1.f / (red[0] + red[1] + red[2] + red[3]);

  for (int k = tid; k < SEQ; k += 256) {
    float p = (k < n) ? buf[k] * inv : 0.f;
    prow[k] = f2bf(p);
  }
}

// ---------------------------------------------------------------------------
// 5) O = P @ V  (P bf16 overlaid in Sc, lda=4096 u16; V as Vt[b][d][s] -> B^T)
//    K-loop bounded causally at (qt+1)*128. fp32 epilogue to d_out.
// ---------------------------------------------------------------------------
__global__ __launch_bounds__(256)
void out_gemm(const float* __restrict__ Sc, const u16* __restrict__ Vt,
              float* __restrict__ Out)
{
  __shared__ u16 As[BM*BK];
  __shared__ u16 Bs[BN*BK];
  const int qt = blockIdx.x;           // 0..15
  const int n0 = blockIdx.y * BN;      // d tile
  const int b  = blockIdx.z;

  const u16* P = (const u16*)(Sc + (size_t)b * SEQ * SEQ);   // lda = 4096 u16
  const u16* V = Vt + (size_t)b * DMODEL * SEQ;              // ldb = 2048
  const int kEnd = (qt + 1) * BM;

  floatx4 acc[4][4] = {};
  gemm_tile_bt(P, 2*SEQ, V, SEQ, qt * BM, n0, kEnd, As, Bs, acc);

  float* O = Out + (size_t)b * SEQ * DMODEL;
  const int lane = threadIdx.x & 63, wave = threadIdx.x >> 6;
  const int wr = wave >> 1, wc = wave & 1;
  const int row0 = qt*BM + wr*64 + (lane >> 4) * 4;
  const int col0 = n0 + wc*64 + (lane & 15);
  #pragma unroll
  for (int m = 0; m < 4; ++m)
    #pragma unroll
    for (int n = 0; n < 4; ++n) {
      int col = col0 + n*16;
      #pragma unroll
      for (int i = 0; i < 4; ++i)
        O[(size_t)(row0 + m*16 + i) * DMODEL + col] = acc[m][n][i];
    }
}

// ---------------------------------------------------------------------------
extern "C" void kernel_launch(void* const* d_in, const int* in_sizes, int n_in,
                              void* d_out, int out_size, void* d_ws, size_t ws_size,
                              hipStream_t stream)
{
  const float* X  = (const float*)d_in[0];
  const float* WQ = (const float*)d_in[1];
  const float* WK = (const float*)d_in[2];
  const float* WV = (const float*)d_in[3];
  float* Out = (float*)d_out;

  char* ws = (char*)d_ws;
  u16*   Xb = (u16*)(ws);                       // 16,777,216 B
  u16*   Wb = (u16*)(ws + 16777216);            //  6,291,456 B
  u16*   Qb = (u16*)(ws + 23068672);            // 16,777,216 B
  u16*   Kb = (u16*)(ws + 39845888);            // 16,777,216 B
  u16*   Vt = (u16*)(ws + 56623104);            // 16,777,216 B
  float* Sc = (float*)(ws + 73400320);          // 67,108,864 B  (total 140.5 MB)

  convert_k<<<dim3(2048), dim3(256), 0, stream>>>(X, WQ, WK, WV, Xb, Wb);
  qkv_gemm<false><<<dim3(64, 8, 2), dim3(256), 0, stream>>>(Xb, Wb, Qb, Kb, Vt);
  qkv_gemm<true ><<<dim3(64, 8, 1), dim3(256), 0, stream>>>(Xb, Wb, Qb, Kb, Vt);
  scores_gemm<<<dim3(136, 4), dim3(256), 0, stream>>>(Qb, Kb, Sc);
  softmax_k<<<dim3(BATCH * SEQ), dim3(256), 0, stream>>>(Sc);
  out_gemm<<<dim3(16, 8, 4), dim3(256), 0, stream>>>(Sc, Vt, Out);
}

// Round 2
// 192.456 us; speedup vs baseline: 1.0382x; 1.0382x over previous
//
#include <hip/hip_runtime.h>

typedef unsigned short u16;
typedef __attribute__((ext_vector_type(8))) short short8;
typedef __attribute__((ext_vector_type(4))) float floatx4;
typedef __attribute__((ext_vector_type(4))) unsigned short ushortx4;

#define BM 128
#define BN 128
#define BK 32

// dims
#define BATCH 4
#define SEQ   2048
#define DMODEL 1024

__device__ __forceinline__ u16 f2bf(float f) {
  unsigned int u = __builtin_bit_cast(unsigned int, f);
  u = (u + 0x7FFFu + ((u >> 16) & 1u)) >> 16;
  return (u16)u;
}

typedef const __attribute__((address_space(1))) unsigned int as1_u32;
typedef __attribute__((address_space(3))) unsigned int as3_u32;

__device__ __forceinline__ void gload16(const void* gp, void* lp) {
  __builtin_amdgcn_global_load_lds((as1_u32*)gp, (as3_u32*)lp, 16, 0, 0);
}

// ---------------------------------------------------------------------------
// Core: C[128x128] tile of A[M][K] @ Bt[N][K]^T, bf16 inputs, fp32 acc.
// 256 threads = 4 waves in 2x2, each wave 64x64 = 4x4 frags of 16x16x32 MFMA.
// Single-buffer LDS, global_load_lds width-16 staging (m97 structure).
// ---------------------------------------------------------------------------
__device__ __forceinline__ void gemm_tile_bt(
    const u16* __restrict__ A, int lda,
    const u16* __restrict__ B, int ldb,
    int m0, int n0, int kEnd,
    u16* As, u16* Bs, floatx4 acc[4][4])
{
  const int tid  = threadIdx.x;
  const int wave = tid >> 6;
  const int lane = tid & 63;
  const int wr = wave >> 1, wc = wave & 1;
  const int r16 = lane & 15;
  const int kk  = (lane >> 4) * 8;
  const int srow = lane >> 2;        // 0..15
  const int scol = (lane & 3) * 8;   // 0,8,16,24

  const u16* gA = A + (size_t)(m0 + 32*wave + srow) * lda + scol;
  const u16* gB = B + (size_t)(n0 + 32*wave + srow) * ldb + scol;
  u16* lA = As + (32*wave)*BK;
  u16* lB = Bs + (32*wave)*BK;

  for (int k0 = 0; k0 < kEnd; k0 += BK) {
    gload16(gA + k0, lA);
    gload16(gA + (size_t)16*lda + k0, lA + 16*BK);
    gload16(gB + k0, lB);
    gload16(gB + (size_t)16*ldb + k0, lB + 16*BK);
    __syncthreads();
    short8 af[4], bfr[4];
    #pragma unroll
    for (int m = 0; m < 4; ++m)
      af[m] = *(const short8*)(As + (wr*64 + m*16 + r16)*BK + kk);
    #pragma unroll
    for (int n = 0; n < 4; ++n)
      bfr[n] = *(const short8*)(Bs + (wc*64 + n*16 + r16)*BK + kk);
    #pragma unroll
    for (int m = 0; m < 4; ++m)
      #pragma unroll
      for (int n = 0; n < 4; ++n)
        acc[m][n] = __builtin_amdgcn_mfma_f32_16x16x32_bf16(af[m], bfr[n], acc[m][n], 0, 0, 0);
    __syncthreads();
  }
}

// ---------------------------------------------------------------------------
// 1) fp32 -> bf16 convert: X (8192x1024) -> Xb ; W_Q/W_K/W_V -> Wb[3][1024][1024]
// ---------------------------------------------------------------------------
__global__ __launch_bounds__(256)
void convert_k(const float* __restrict__ X,
               const float* __restrict__ WQ,
               const float* __restrict__ WK,
               const float* __restrict__ WV,
               u16* __restrict__ Xb, u16* __restrict__ Wb)
{
  const int NX = (BATCH*SEQ*DMODEL) / 4;   // float4 units: 2,097,152
  const int NW = (DMODEL*DMODEL) / 4;      // 262,144
  const int total = NX + 3*NW;
  for (int i = blockIdx.x * 256 + threadIdx.x; i < total; i += gridDim.x * 256) {
    const float4* src; u16* dst; int j;
    if (i < NX) { src = (const float4*)X; j = i; dst = Xb; }
    else {
      int t = i - NX; int w = t / NW; j = t - w * NW;
      src = (const float4*)(w == 0 ? WQ : (w == 1 ? WK : WV));
      dst = Wb + (size_t)w * (DMODEL*DMODEL);
    }
    float4 v = src[j];
    ushortx4 p = { f2bf(v.x), f2bf(v.y), f2bf(v.z), f2bf(v.w) };
    *(ushortx4*)(dst + (size_t)j * 4) = p;
  }
}

// ---------------------------------------------------------------------------
// 2) Fused QKV projection: one launch, z in {0,1,2} -> Q, K (row-major bf16),
//    V written batch-transposed Vt[b][d][s]. 1D grid, XCD-chunked swizzle.
// ---------------------------------------------------------------------------
__global__ __launch_bounds__(256)
void qkv_gemm_all(const u16* __restrict__ Xb, const u16* __restrict__ Wb,
                  u16* __restrict__ Q, u16* __restrict__ K, u16* __restrict__ Vt)
{
  __shared__ u16 As[BM*BK];
  __shared__ u16 Bs[BN*BK];

  // bijective XCD-chunked swizzle (nwg = 1536, 1536 % 8 == 0)
  const int nwg = 64*8*3, cpx = nwg/8;
  int id = blockIdx.x;
  int sw = (id & 7) * cpx + (id >> 3);
  const int z   = sw >> 9;             // /512: which of Q,K,V
  const int rem = sw & 511;
  const int mt  = rem >> 3;            // 0..63 (n0 fastest -> A-panel reuse)
  const int nt  = rem & 7;             // 0..7
  const int m0 = mt * BM;
  const int n0 = nt * BN;
  const u16* W = Wb + (size_t)z * (DMODEL*DMODEL);

  floatx4 acc[4][4] = {};
  gemm_tile_bt(Xb, DMODEL, W, DMODEL, m0, n0, DMODEL, As, Bs, acc);

  const int lane = threadIdx.x & 63, wave = threadIdx.x >> 6;
  const int wr = wave >> 1, wc = wave & 1;
  const int row0 = m0 + wr*64 + (lane >> 4) * 4;
  const int col0 = n0 + wc*64 + (lane & 15);

  if (z < 2) {
    u16* O = (z == 0) ? Q : K;
    #pragma unroll
    for (int m = 0; m < 4; ++m)
      #pragma unroll
      for (int n = 0; n < 4; ++n) {
        int col = col0 + n*16;
        #pragma unroll
        for (int i = 0; i < 4; ++i)
          O[(size_t)(row0 + m*16 + i) * DMODEL + col] = f2bf(acc[m][n][i]);
      }
  } else {
    #pragma unroll
    for (int m = 0; m < 4; ++m) {
      int gm = row0 + m*16;
      int b = gm >> 11, s = gm & (SEQ - 1);
      #pragma unroll
      for (int n = 0; n < 4; ++n) {
        int d = col0 + n*16;
        ushortx4 p = { f2bf(acc[m][n][0]), f2bf(acc[m][n][1]),
                       f2bf(acc[m][n][2]), f2bf(acc[m][n][3]) };
        *(ushortx4*)(Vt + ((size_t)b * DMODEL + d) * SEQ + s) = p;
      }
    }
  }
}

// ---------------------------------------------------------------------------
// 3) scores = Q @ K^T / 32, lower-triangular tiles only, fp32 out
// ---------------------------------------------------------------------------
__global__ __launch_bounds__(256)
void scores_gemm(const u16* __restrict__ Qb, const u16* __restrict__ Kb,
                 float* __restrict__ Sc)
{
  __shared__ u16 As[BM*BK];
  __shared__ u16 Bs[BN*BK];
  const int b = blockIdx.y;
  const int t = blockIdx.x;             // 0..135 triangular
  int qt = 0;
  while ((qt + 1) * (qt + 2) / 2 <= t) ++qt;
  const int kt = t - qt * (qt + 1) / 2;

  const u16* Q = Qb + (size_t)b * SEQ * DMODEL;
  const u16* K = Kb + (size_t)b * SEQ * DMODEL;

  floatx4 acc[4][4] = {};
  gemm_tile_bt(Q, DMODEL, K, DMODEL, qt * BM, kt * BN, DMODEL, As, Bs, acc);

  float* S = Sc + (size_t)b * SEQ * SEQ;
  const int lane = threadIdx.x & 63, wave = threadIdx.x >> 6;
  const int wr = wave >> 1, wc = wave & 1;
  const int row0 = qt*BM + wr*64 + (lane >> 4) * 4;
  const int col0 = kt*BN + wc*64 + (lane & 15);
  #pragma unroll
  for (int m = 0; m < 4; ++m)
    #pragma unroll
    for (int n = 0; n < 4; ++n) {
      int col = col0 + n*16;
      #pragma unroll
      for (int i = 0; i < 4; ++i)
        S[(size_t)(row0 + m*16 + i) * SEQ + col] = acc[m][n][i] * 0.03125f;
    }
}

// ---------------------------------------------------------------------------
// 4) causal row softmax, in-place: fp32 row -> bf16 P overlaid at row start
//    (P element k at u16 index k; row slot stride stays 8KB = 4096 u16)
//    Zero-fill only up to the causal 128-tile boundary (out_gemm reads no further).
// ---------------------------------------------------------------------------
__global__ __launch_bounds__(256)
void softmax_k(float* __restrict__ Sc)
{
  __shared__ float buf[SEQ];
  __shared__ float red[4];
  const int rg = blockIdx.x;           // 0..8191
  const int q = rg & (SEQ - 1);
  float* row = Sc + (size_t)rg * SEQ;
  u16* prow = (u16*)row;
  const int tid = threadIdx.x;
  const int lane = tid & 63, wave = tid >> 6;
  const int n = q + 1;
  const int kpad = ((q >> 7) + 1) << 7;  // causal tile boundary

  float lmax = -3.4e38f;
  for (int k = tid; k < n; k += 256) {
    float v = row[k];
    buf[k] = v;
    lmax = fmaxf(lmax, v);
  }
  #pragma unroll
  for (int off = 32; off >= 1; off >>= 1)
    lmax = fmaxf(lmax, __shfl_xor(lmax, off));
  if (lane == 0) red[wave] = lmax;
  __syncthreads();
  const float rmax = fmaxf(fmaxf(red[0], red[1]), fmaxf(red[2], red[3]));
  __syncthreads();

  float lsum = 0.f;
  for (int k = tid; k < n; k += 256) {
    float e = __expf(buf[k] - rmax);
    buf[k] = e;
    lsum += e;
  }
  #pragma unroll
  for (int off = 32; off >= 1; off >>= 1)
    lsum += __shfl_xor(lsum, off);
  if (lane == 0) red[wave] = lsum;
  __syncthreads();
  const float inv = 1.f / (red[0] + red[1] + red[2] + red[3]);

  for (int k = tid; k < kpad; k += 256) {
    float p = (k < n) ? buf[k] * inv : 0.f;
    prow[k] = f2bf(p);
  }
}

// ---------------------------------------------------------------------------
// 5) O = P @ V  (P bf16 overlaid in Sc, lda=4096 u16; V as Vt[b][d][s] -> B^T)
//    K-loop bounded causally at (qt+1)*128. fp32 epilogue to d_out.
//    1D grid of 512 with complement-pairing: blocks i and i+256 get qt and
//    15-qt, so each CU's 2 resident blocks sum to a constant 68 K-iters;
//    second half is emitted qt-descending (LPT under greedy backfill).
// ---------------------------------------------------------------------------
__global__ __launch_bounds__(256)
void out_gemm(const float* __restrict__ Sc, const u16* __restrict__ Vt,
              float* __restrict__ Out)
{
  __shared__ u16 As[BM*BK];
  __shared__ u16 Bs[BN*BK];

  const int i = blockIdx.x;            // 0..511
  const int j = i & 255;
  const int upper = i >> 8;            // 0 or 1
  const int qraw = j & 15;
  const int qt = upper ? (15 - qraw) : qraw;
  const int nt = (j >> 4) & 7;
  const int b  = (upper << 1) | (j >> 7);
  const int n0 = nt * BN;

  const u16* P = (const u16*)(Sc + (size_t)b * SEQ * SEQ);   // lda = 4096 u16
  const u16* V = Vt + (size_t)b * DMODEL * SEQ;              // ldb = 2048
  const int kEnd = (qt + 1) * BM;

  floatx4 acc[4][4] = {};
  gemm_tile_bt(P, 2*SEQ, V, SEQ, qt * BM, n0, kEnd, As, Bs, acc);

  float* O = Out + (size_t)b * SEQ * DMODEL;
  const int lane = threadIdx.x & 63, wave = threadIdx.x >> 6;
  const int wr = wave >> 1, wc = wave & 1;
  const int row0 = qt*BM + wr*64 + (lane >> 4) * 4;
  const int col0 = n0 + wc*64 + (lane & 15);
  #pragma unroll
  for (int m = 0; m < 4; ++m)
    #pragma unroll
    for (int n = 0; n < 4; ++n) {
      int col = col0 + n*16;
      #pragma unroll
      for (int i2 = 0; i2 < 4; ++i2)
        O[(size_t)(row0 + m*16 + i2) * DMODEL + col] = acc[m][n][i2];
    }
}

// ---------------------------------------------------------------------------
extern "C" void kernel_launch(void* const* d_in, const int* in_sizes, int n_in,
                              void* d_out, int out_size, void* d_ws, size_t ws_size,
                              hipStream_t stream)
{
  const float* X  = (const float*)d_in[0];
  const float* WQ = (const float*)d_in[1];
  const float* WK = (const float*)d_in[2];
  const float* WV = (const float*)d_in[3];
  float* Out = (float*)d_out;

  char* ws = (char*)d_ws;
  u16*   Xb = (u16*)(ws);                       // 16,777,216 B
  u16*   Wb = (u16*)(ws + 16777216);            //  6,291,456 B
  u16*   Qb = (u16*)(ws + 23068672);            // 16,777,216 B
  u16*   Kb = (u16*)(ws + 39845888);            // 16,777,216 B
  u16*   Vt = (u16*)(ws + 56623104);            // 16,777,216 B
  float* Sc = (float*)(ws + 73400320);          // 67,108,864 B  (total 140.5 MB)

  convert_k<<<dim3(2048), dim3(256), 0, stream>>>(X, WQ, WK, WV, Xb, Wb);
  qkv_gemm_all<<<dim3(64*8*3), dim3(256), 0, stream>>>(Xb, Wb, Qb, Kb, Vt);
  scores_gemm<<<dim3(136, 4), dim3(256), 0, stream>>>(Qb, Kb, Sc);
  softmax_k<<<dim3(BATCH * SEQ), dim3(256), 0, stream>>>(Sc);
  out_gemm<<<dim3(512), dim3(256), 0, stream>>>(Sc, Vt, Out);
}

// Round 3
// 178.630 us; speedup vs baseline: 1.1185x; 1.0774x over previous
//
#include <hip/hip_runtime.h>

typedef unsigned short u16;
typedef __attribute__((ext_vector_type(8))) short short8;
typedef __attribute__((ext_vector_type(4))) float floatx4;
typedef __attribute__((ext_vector_type(4))) unsigned short ushortx4;

#define BATCH 4
#define SEQ   2048
#define DMODEL 1024

// 8-phase GEMM geometry: 256x128 tile, BK=64, 8 waves (4M x 2N), 512 threads
#define GBM 256
#define GBN 128
#define GBK 64
#define LDSHALF 24576   // (GBM+GBN)*GBK u16 per buffer
#define BBUF    16384   // GBM*GBK u16: offset of B tile within buffer

__device__ __forceinline__ u16 f2bf(float f) {
  unsigned int u = __builtin_bit_cast(unsigned int, f);
  u = (u + 0x7FFFu + ((u >> 16) & 1u)) >> 16;
  return (u16)u;
}

typedef const __attribute__((address_space(1))) unsigned int as1_u32;
typedef __attribute__((address_space(3))) unsigned int as3_u32;

__device__ __forceinline__ void gload16(const void* gp, void* lp) {
  __builtin_amdgcn_global_load_lds((as1_u32*)gp, (as3_u32*)lp, 16, 0, 0);
}

// ---------------------------------------------------------------------------
// Stage one K-tile (A: 256x64, B: 128x64 bf16) into LDS buffer `buf`.
// LDS dest is LINEAR (global_load_lds writes base + lane*16); the XOR swizzle
// is applied on the GLOBAL source slot (inverse == same involution), so
// readers use addr ^ ((row&7)<<3).  6 gloads/thread total (4 A + 2 B).
// ---------------------------------------------------------------------------
__device__ __forceinline__ void stage_tile(
    const u16* __restrict__ A, int lda,
    const u16* __restrict__ B, int ldb,
    int m0, int n0, int kt, u16* buf, int w, int l)
{
  const int lr = l >> 3;    // row-within-8
  const int s  = l & 7;     // 16B slot within 128B row
  #pragma unroll
  for (int i = 0; i < 4; ++i) {
    int row = i*64 + w*8 + lr;
    const u16* src = A + (size_t)(m0 + row) * lda + kt*GBK + ((s ^ (row & 7)) << 3);
    gload16(src, buf + i*4096 + w*512);
  }
  #pragma unroll
  for (int j = 0; j < 2; ++j) {
    int row = j*64 + w*8 + lr;
    const u16* src = B + (size_t)(n0 + row) * ldb + kt*GBK + ((s ^ (row & 7)) << 3);
    gload16(src, buf + BBUF + j*4096 + w*512);
  }
}

__device__ __forceinline__ short8 rdA(const u16* buf, int wr, int m, int kh, int lane) {
  int r = wr*64 + m*16 + (lane & 15);
  int c = kh*32 + ((lane >> 4) << 3);
  int off = (r*64 + c) ^ ((r & 7) << 3);
  return *(const short8*)(buf + off);
}
__device__ __forceinline__ short8 rdB(const u16* buf, int wc, int n, int kh, int lane) {
  int r = wc*64 + n*16 + (lane & 15);
  int c = kh*32 + ((lane >> 4) << 3);
  int off = (r*64 + c) ^ ((r & 7) << 3);
  return *(const short8*)(buf + BBUF + off);
}

#define CFENCE asm volatile("" ::: "memory")

// ---------------------------------------------------------------------------
// Deep-pipelined Bt-form GEMM core: C[256x128] += A[m0:+256][0:NT*64] @ B^T.
// Double-buffered LDS; stage of tile kt+1 issued at top of iter kt; counted
// vmcnt(6) (never 0 in steady state); 4 MFMA phases per K-tile with raw
// barriers, lgkmcnt(0)+sched_barrier, setprio around MFMA clusters.
// ---------------------------------------------------------------------------
__device__ __forceinline__ void gemm8_core(
    const u16* __restrict__ A, int lda,
    const u16* __restrict__ B, int ldb,
    int m0, int n0, int NT, u16* lds, floatx4 acc[4][4])
{
  const int tid = threadIdx.x;
  const int w = tid >> 6, l = tid & 63;
  const int wr = w >> 1, wc = w & 1;

  stage_tile(A, lda, B, ldb, m0, n0, 0, lds, w, l);

  for (int kt = 0; kt < NT; ++kt) {
    u16* cur = lds + (kt & 1) * LDSHALF;
    if (kt + 1 < NT) {
      stage_tile(A, lda, B, ldb, m0, n0, kt + 1, lds + ((kt + 1) & 1) * LDSHALF, w, l);
      asm volatile("s_waitcnt vmcnt(6)" ::: "memory");   // retire tile kt's 6 loads
    } else {
      asm volatile("s_waitcnt vmcnt(0)" ::: "memory");
    }
    __builtin_amdgcn_s_barrier();   // all waves' stage of cur complete
    CFENCE;

    short8 aLo[2][2], aHi[2][2], bLo[2][2], bHi[2][2];

    // ---- phase 0: read A[0,1],B[0,1]; mfma m01 x n01
    #pragma unroll
    for (int m = 0; m < 2; ++m)
      #pragma unroll
      for (int k = 0; k < 2; ++k) aLo[m][k] = rdA(cur, wr, m, k, l);
    #pragma unroll
    for (int n = 0; n < 2; ++n)
      #pragma unroll
      for (int k = 0; k < 2; ++k) bLo[n][k] = rdB(cur, wc, n, k, l);
    __builtin_amdgcn_s_barrier();
    asm volatile("s_waitcnt lgkmcnt(0)" ::: "memory");
    __builtin_amdgcn_sched_barrier(0);
    __builtin_amdgcn_s_setprio(1);
    #pragma unroll
    for (int m = 0; m < 2; ++m)
      #pragma unroll
      for (int n = 0; n < 2; ++n)
        #pragma unroll
        for (int k = 0; k < 2; ++k)
          acc[m][n] = __builtin_amdgcn_mfma_f32_16x16x32_bf16(aLo[m][k], bLo[n][k], acc[m][n], 0, 0, 0);
    __builtin_amdgcn_s_setprio(0);
    __builtin_amdgcn_s_barrier();
    CFENCE;

    // ---- phase 1: read B[2,3]; mfma m01 x n23
    #pragma unroll
    for (int n = 0; n < 2; ++n)
      #pragma unroll
      for (int k = 0; k < 2; ++k) bHi[n][k] = rdB(cur, wc, n + 2, k, l);
    __builtin_amdgcn_s_barrier();
    asm volatile("s_waitcnt lgkmcnt(0)" ::: "memory");
    __builtin_amdgcn_sched_barrier(0);
    __builtin_amdgcn_s_setprio(1);
    #pragma unroll
    for (int m = 0; m < 2; ++m)
      #pragma unroll
      for (int n = 0; n < 2; ++n)
        #pragma unroll
        for (int k = 0; k < 2; ++k)
          acc[m][n + 2] = __builtin_amdgcn_mfma_f32_16x16x32_bf16(aLo[m][k], bHi[n][k], acc[m][n + 2], 0, 0, 0);
    __builtin_amdgcn_s_setprio(0);
    __builtin_amdgcn_s_barrier();
    CFENCE;

    // ---- phase 2: read A[2,3]; mfma m23 x n23
    #pragma unroll
    for (int m = 0; m < 2; ++m)
      #pragma unroll
      for (int k = 0; k < 2; ++k) aHi[m][k] = rdA(cur, wr, m + 2, k, l);
    __builtin_amdgcn_s_barrier();
    asm volatile("s_waitcnt lgkmcnt(0)" ::: "memory");
    __builtin_amdgcn_sched_barrier(0);
    __builtin_amdgcn_s_setprio(1);
    #pragma unroll
    for (int m = 0; m < 2; ++m)
      #pragma unroll
      for (int n = 0; n < 2; ++n)
        #pragma unroll
        for (int k = 0; k < 2; ++k)
          acc[m + 2][n + 2] = __builtin_amdgcn_mfma_f32_16x16x32_bf16(aHi[m][k], bHi[n][k], acc[m + 2][n + 2], 0, 0, 0);
    __builtin_amdgcn_s_setprio(0);
    __builtin_amdgcn_s_barrier();
    CFENCE;

    // ---- phase 3: no reads; mfma m23 x n01 (bLo still live)
    __builtin_amdgcn_s_setprio(1);
    #pragma unroll
    for (int m = 0; m < 2; ++m)
      #pragma unroll
      for (int n = 0; n < 2; ++n)
        #pragma unroll
        for (int k = 0; k < 2; ++k)
          acc[m + 2][n] = __builtin_amdgcn_mfma_f32_16x16x32_bf16(aHi[m][k], bLo[n][k], acc[m + 2][n], 0, 0, 0);
    __builtin_amdgcn_s_setprio(0);
    __builtin_amdgcn_s_barrier();   // protect cur: next iter stages into it
    CFENCE;
  }
}

// ---------------------------------------------------------------------------
// 1) fp32 -> bf16 convert
// ---------------------------------------------------------------------------
__global__ __launch_bounds__(256)
void convert_k(const float* __restrict__ X,
               const float* __restrict__ WQ,
               const float* __restrict__ WK,
               const float* __restrict__ WV,
               u16* __restrict__ Xb, u16* __restrict__ Wb)
{
  const int NX = (BATCH*SEQ*DMODEL) / 4;
  const int NW = (DMODEL*DMODEL) / 4;
  const int total = NX + 3*NW;
  for (int i = blockIdx.x * 256 + threadIdx.x; i < total; i += gridDim.x * 256) {
    const float4* src; u16* dst; int j;
    if (i < NX) { src = (const float4*)X; j = i; dst = Xb; }
    else {
      int t = i - NX; int w = t / NW; j = t - w * NW;
      src = (const float4*)(w == 0 ? WQ : (w == 1 ? WK : WV));
      dst = Wb + (size_t)w * (DMODEL*DMODEL);
    }
    float4 v = src[j];
    ushortx4 p = { f2bf(v.x), f2bf(v.y), f2bf(v.z), f2bf(v.w) };
    *(ushortx4*)(dst + (size_t)j * 4) = p;
  }
}

// ---------------------------------------------------------------------------
// 2) QKV projection, 768 blocks (exactly 3 CU-rounds), XCD-chunked swizzle
// ---------------------------------------------------------------------------
__global__ __launch_bounds__(512, 1)
void qkv8(const u16* __restrict__ Xb, const u16* __restrict__ Wb,
          u16* __restrict__ Q, u16* __restrict__ K, u16* __restrict__ Vt)
{
  __shared__ u16 lds[2*LDSHALF];
  const int id = blockIdx.x;
  const int sw = (id & 7) * 96 + (id >> 3);   // 768 % 8 == 0, bijective
  const int mt = sw / 24, r = sw % 24;
  const int z = r >> 3, nt = r & 7;
  const int m0 = mt * GBM, n0 = nt * GBN;

  floatx4 acc[4][4] = {};
  gemm8_core(Xb, DMODEL, Wb + (size_t)z * DMODEL * DMODEL, DMODEL,
             m0, n0, DMODEL/GBK, lds, acc);

  const int l = threadIdx.x & 63, w = threadIdx.x >> 6;
  const int wr = w >> 1, wc = w & 1;
  const int row0 = m0 + wr*64 + ((l >> 4) << 2);
  const int col0 = n0 + wc*64 + (l & 15);

  if (z < 2) {
    u16* O = z ? K : Q;
    #pragma unroll
    for (int m = 0; m < 4; ++m)
      #pragma unroll
      for (int n = 0; n < 4; ++n)
        #pragma unroll
        for (int i = 0; i < 4; ++i)
          O[(size_t)(row0 + m*16 + i) * DMODEL + col0 + n*16] = f2bf(acc[m][n][i]);
  } else {
    #pragma unroll
    for (int m = 0; m < 4; ++m) {
      int gm = row0 + m*16;
      int b = gm >> 11, s = gm & (SEQ - 1);
      #pragma unroll
      for (int n = 0; n < 4; ++n) {
        int d = col0 + n*16;
        ushortx4 p = { f2bf(acc[m][n][0]), f2bf(acc[m][n][1]),
                       f2bf(acc[m][n][2]), f2bf(acc[m][n][3]) };
        *(ushortx4*)(Vt + ((size_t)b * DMODEL + d) * SEQ + s) = p;
      }
    }
  }
}

// ---------------------------------------------------------------------------
// 3) scores = Q @ K^T / 32, causal 256x128 tiles only (72/batch, 288 blocks)
// ---------------------------------------------------------------------------
__global__ __launch_bounds__(512, 1)
void scores8(const u16* __restrict__ Qb, const u16* __restrict__ Kb,
             float* __restrict__ Sc)
{
  __shared__ u16 lds[2*LDSHALF];
  const int id = blockIdx.x;
  const int sw = (id & 7) * 36 + (id >> 3);   // 288 % 8 == 0
  const int b = sw / 72;
  const int t = sw % 72;
  int qt = 0;
  while ((qt + 1) * (qt + 2) <= t) ++qt;      // cum(qt) = qt*(qt+1)
  const int nt = t - qt * (qt + 1);           // 0 .. 2qt+1
  const int m0 = qt * GBM, n0 = nt * GBN;

  const u16* Q = Qb + (size_t)b * SEQ * DMODEL;
  const u16* K = Kb + (size_t)b * SEQ * DMODEL;
  floatx4 acc[4][4] = {};
  gemm8_core(Q, DMODEL, K, DMODEL, m0, n0, DMODEL/GBK, lds, acc);

  float* S = Sc + (size_t)b * SEQ * SEQ;
  const int l = threadIdx.x & 63, w = threadIdx.x >> 6;
  const int wr = w >> 1, wc = w & 1;
  const int row0 = m0 + wr*64 + ((l >> 4) << 2);
  const int col0 = n0 + wc*64 + (l & 15);
  #pragma unroll
  for (int m = 0; m < 4; ++m)
    #pragma unroll
    for (int n = 0; n < 4; ++n)
      #pragma unroll
      for (int i = 0; i < 4; ++i)
        S[(size_t)(row0 + m*16 + i) * SEQ + col0 + n*16] = acc[m][n][i] * 0.03125f;
}

// ---------------------------------------------------------------------------
// 4) causal row softmax, in-place bf16 P overlay; zero-fill to 256-boundary
//    (out8's A-tiles read exactly kEnd = 256-aligned causal span)
// ---------------------------------------------------------------------------
__global__ __launch_bounds__(256)
void softmax_k(float* __restrict__ Sc)
{
  __shared__ float buf[SEQ];
  __shared__ float red[4];
  const int rg = blockIdx.x;
  const int q = rg & (SEQ - 1);
  float* row = Sc + (size_t)rg * SEQ;
  u16* prow = (u16*)row;
  const int tid = threadIdx.x;
  const int lane = tid & 63, wave = tid >> 6;
  const int n = q + 1;
  const int kpad = ((q >> 8) + 1) << 8;   // 256-tile boundary

  float lmax = -3.4e38f;
  for (int k = tid; k < n; k += 256) {
    float v = row[k];
    buf[k] = v;
    lmax = fmaxf(lmax, v);
  }
  #pragma unroll
  for (int off = 32; off >= 1; off >>= 1)
    lmax = fmaxf(lmax, __shfl_xor(lmax, off));
  if (lane == 0) red[wave] = lmax;
  __syncthreads();
  const float rmax = fmaxf(fmaxf(red[0], red[1]), fmaxf(red[2], red[3]));
  __syncthreads();

  float lsum = 0.f;
  for (int k = tid; k < n; k += 256) {
    float e = __expf(buf[k] - rmax);
    buf[k] = e;
    lsum += e;
  }
  #pragma unroll
  for (int off = 32; off >= 1; off >>= 1)
    lsum += __shfl_xor(lsum, off);
  if (lane == 0) red[wave] = lsum;
  __syncthreads();
  const float inv = 1.f / (red[0] + red[1] + red[2] + red[3]);

  for (int k = tid; k < kpad; k += 256) {
    float p = (k < n) ? buf[k] * inv : 0.f;
    prow[k] = f2bf(p);
  }
}

// ---------------------------------------------------------------------------
// 5) O = P @ V, causal K bound; 256 blocks = 1 full CU-round
// ---------------------------------------------------------------------------
__global__ __launch_bounds__(512, 1)
void out8(const float* __restrict__ Sc, const u16* __restrict__ Vt,
          float* __restrict__ Out)
{
  __shared__ u16 lds[2*LDSHALF];
  const int id = blockIdx.x;
  const int qt = id & 7;          // qt varies fastest -> uniform XCD mix
  const int b  = (id >> 3) & 3;
  const int nt = id >> 5;
  const int m0 = qt * GBM, n0 = nt * GBN;

  const u16* P = (const u16*)(Sc + (size_t)b * SEQ * SEQ);  // lda = 2*SEQ u16
  const u16* V = Vt + (size_t)b * DMODEL * SEQ;             // ldb = SEQ
  const int NT = (qt + 1) * (GBM / GBK);

  floatx4 acc[4][4] = {};
  gemm8_core(P, 2*SEQ, V, SEQ, m0, n0, NT, lds, acc);

  float* O = Out + (size_t)b * SEQ * DMODEL;
  const int l = threadIdx.x & 63, w = threadIdx.x >> 6;
  const int wr = w >> 1, wc = w & 1;
  const int row0 = m0 + wr*64 + ((l >> 4) << 2);
  const int col0 = n0 + wc*64 + (l & 15);
  #pragma unroll
  for (int m = 0; m < 4; ++m)
    #pragma unroll
    for (int n = 0; n < 4; ++n)
      #pragma unroll
      for (int i = 0; i < 4; ++i)
        O[(size_t)(row0 + m*16 + i) * DMODEL + col0 + n*16] = acc[m][n][i];
}

// ---------------------------------------------------------------------------
extern "C" void kernel_launch(void* const* d_in, const int* in_sizes, int n_in,
                              void* d_out, int out_size, void* d_ws, size_t ws_size,
                              hipStream_t stream)
{
  const float* X  = (const float*)d_in[0];
  const float* WQ = (const float*)d_in[1];
  const float* WK = (const float*)d_in[2];
  const float* WV = (const float*)d_in[3];
  float* Out = (float*)d_out;

  char* ws = (char*)d_ws;
  u16*   Xb = (u16*)(ws);                       // 16,777,216 B
  u16*   Wb = (u16*)(ws + 16777216);            //  6,291,456 B
  u16*   Qb = (u16*)(ws + 23068672);            // 16,777,216 B
  u16*   Kb = (u16*)(ws + 39845888);            // 16,777,216 B
  u16*   Vt = (u16*)(ws + 56623104);            // 16,777,216 B
  float* Sc = (float*)(ws + 73400320);          // 67,108,864 B

  convert_k<<<dim3(2048), dim3(256), 0, stream>>>(X, WQ, WK, WV, Xb, Wb);
  qkv8<<<dim3(768), dim3(512), 0, stream>>>(Xb, Wb, Qb, Kb, Vt);
  scores8<<<dim3(288), dim3(512), 0, stream>>>(Qb, Kb, Sc);
  softmax_k<<<dim3(BATCH * SEQ), dim3(256), 0, stream>>>(Sc);
  out8<<<dim3(256), dim3(512), 0, stream>>>(Sc, Vt, Out);
}

// Round 4
// 167.190 us; speedup vs baseline: 1.1950x; 1.0684x over previous
//
#include <hip/hip_runtime.h>

typedef unsigned short u16;
typedef __attribute__((ext_vector_type(8))) short short8;
typedef __attribute__((ext_vector_type(4))) float floatx4;
typedef __attribute__((ext_vector_type(4))) unsigned short ushortx4;

#define BATCH 4
#define SEQ   2048
#define DMODEL 1024

// GEMM geometry: 256x128 tile, BK=64, 8 waves (4M x 2N), 512 threads
#define GBM 256
#define GBN 128
#define GBK 64
#define LDSHALF 24576   // (GBM+GBN)*GBK u16 per buffer
#define BBUF    16384   // GBM*GBK u16: offset of B tile within buffer

__device__ __forceinline__ u16 f2bf(float f) {
  unsigned int u = __builtin_bit_cast(unsigned int, f);
  u = (u + 0x7FFFu + ((u >> 16) & 1u)) >> 16;
  return (u16)u;
}

typedef const __attribute__((address_space(1))) unsigned int as1_u32;
typedef __attribute__((address_space(3))) unsigned int as3_u32;

__device__ __forceinline__ void gload16(const void* gp, void* lp) {
  __builtin_amdgcn_global_load_lds((as1_u32*)gp, (as3_u32*)lp, 16, 0, 0);
}

// ---------------------------------------------------------------------------
// Staging chunks: LDS dest LINEAR (DMA writes base + lane*16); XOR swizzle is
// applied on the GLOBAL source 16B-slot; readers use addr ^ ((row&7)<<3).
// Each chunk = 2 global_load_lds per thread. 3 chunks per K-tile (A0,A1,B).
// ---------------------------------------------------------------------------
__device__ __forceinline__ void stage_chunkA(
    const u16* __restrict__ A, int lda, int m0, int kt, u16* buf,
    int half, int w, int l)
{
  const int lr = l >> 3, s = l & 7;
  #pragma unroll
  for (int i = 2*half; i < 2*half + 2; ++i) {
    int row = i*64 + w*8 + lr;
    const u16* src = A + (size_t)(m0 + row) * lda + kt*GBK + ((s ^ (row & 7)) << 3);
    gload16(src, buf + i*4096 + w*512);
  }
}
__device__ __forceinline__ void stage_chunkB(
    const u16* __restrict__ B, int ldb, int n0, int kt, u16* buf, int w, int l)
{
  const int lr = l >> 3, s = l & 7;
  #pragma unroll
  for (int j = 0; j < 2; ++j) {
    int row = j*64 + w*8 + lr;
    const u16* src = B + (size_t)(n0 + row) * ldb + kt*GBK + ((s ^ (row & 7)) << 3);
    gload16(src, buf + BBUF + j*4096 + w*512);
  }
}

__device__ __forceinline__ short8 rdA(const u16* buf, int wr, int m, int kh, int lane) {
  int r = wr*64 + m*16 + (lane & 15);
  int c = kh*32 + ((lane >> 4) << 3);
  int off = (r*64 + c) ^ ((r & 7) << 3);
  return *(const short8*)(buf + off);
}
__device__ __forceinline__ short8 rdB(const u16* buf, int wc, int n, int kh, int lane) {
  int r = wc*64 + n*16 + (lane & 15);
  int c = kh*32 + ((lane >> 4) << 3);
  int off = (r*64 + c) ^ ((r & 7) << 3);
  return *(const short8*)(buf + BBUF + off);
}

#define CFENCE asm volatile("" ::: "memory")
#define LGKM0  do { asm volatile("s_waitcnt lgkmcnt(0)" ::: "memory"); \
                    __builtin_amdgcn_sched_barrier(0); } while (0)

// ---------------------------------------------------------------------------
// Deep-pipelined Bt-form GEMM core: C[256x128] += A @ B^T over NT K-tiles.
// 3-buffer LDS ring, 2-tile prefetch depth; stage chunks of tile kt+2 spread
// one-per-phase (fine interleave); counted vmcnt(6) once per tile (never 0
// in steady state); raw barriers + lgkmcnt(0)+sched_barrier; setprio on MFMA.
// ---------------------------------------------------------------------------
__device__ __forceinline__ void gemm8_core(
    const u16* __restrict__ A, int lda,
    const u16* __restrict__ B, int ldb,
    int m0, int n0, int NT, u16* lds, floatx4 acc[4][4])
{
  const int tid = threadIdx.x;
  const int w = tid >> 6, l = tid & 63;
  const int wr = w >> 1, wc = w & 1;

  // prologue: stage tiles 0 and 1
  stage_chunkA(A, lda, m0, 0, lds, 0, w, l);
  stage_chunkA(A, lda, m0, 0, lds, 1, w, l);
  stage_chunkB(B, ldb, n0, 0, lds, w, l);
  if (NT > 1) {
    stage_chunkA(A, lda, m0, 1, lds + LDSHALF, 0, w, l);
    stage_chunkA(A, lda, m0, 1, lds + LDSHALF, 1, w, l);
    stage_chunkB(B, ldb, n0, 1, lds + LDSHALF, w, l);
    asm volatile("s_waitcnt vmcnt(6)" ::: "memory");   // tile 0 resident
  } else {
    asm volatile("s_waitcnt vmcnt(0)" ::: "memory");
  }
  __builtin_amdgcn_s_barrier();
  CFENCE;

  for (int kt = 0; kt < NT; ++kt) {
    u16* cur = lds + (kt % 3) * LDSHALF;
    u16* nxt = lds + ((kt + 2) % 3) * LDSHALF;
    const bool st = (kt + 2 < NT);

    short8 aLo[2][2], aHi[2][2], bLo[2][2], bHi[2][2];

    // ---- phase 0: read A[0,1]+B[0,1]; stage A-half0(kt+2); mfma m01 x n01
    #pragma unroll
    for (int m = 0; m < 2; ++m)
      #pragma unroll
      for (int k = 0; k < 2; ++k) aLo[m][k] = rdA(cur, wr, m, k, l);
    #pragma unroll
    for (int n = 0; n < 2; ++n)
      #pragma unroll
      for (int k = 0; k < 2; ++k) bLo[n][k] = rdB(cur, wc, n, k, l);
    if (st) stage_chunkA(A, lda, m0, kt + 2, nxt, 0, w, l);
    __builtin_amdgcn_s_barrier();
    LGKM0;
    __builtin_amdgcn_s_setprio(1);
    #pragma unroll
    for (int m = 0; m < 2; ++m)
      #pragma unroll
      for (int n = 0; n < 2; ++n)
        #pragma unroll
        for (int k = 0; k < 2; ++k)
          acc[m][n] = __builtin_amdgcn_mfma_f32_16x16x32_bf16(aLo[m][k], bLo[n][k], acc[m][n], 0, 0, 0);
    __builtin_amdgcn_s_setprio(0);
    __builtin_amdgcn_s_barrier();
    CFENCE;

    // ---- phase 1: read B[2,3]; stage A-half1(kt+2); mfma m01 x n23
    #pragma unroll
    for (int n = 0; n < 2; ++n)
      #pragma unroll
      for (int k = 0; k < 2; ++k) bHi[n][k] = rdB(cur, wc, n + 2, k, l);
    if (st) stage_chunkA(A, lda, m0, kt + 2, nxt, 1, w, l);
    __builtin_amdgcn_s_barrier();
    LGKM0;
    __builtin_amdgcn_s_setprio(1);
    #pragma unroll
    for (int m = 0; m < 2; ++m)
      #pragma unroll
      for (int n = 0; n < 2; ++n)
        #pragma unroll
        for (int k = 0; k < 2; ++k)
          acc[m][n + 2] = __builtin_amdgcn_mfma_f32_16x16x32_bf16(aLo[m][k], bHi[n][k], acc[m][n + 2], 0, 0, 0);
    __builtin_amdgcn_s_setprio(0);
    __builtin_amdgcn_s_barrier();
    CFENCE;

    // ---- phase 2: read A[2,3]; stage B(kt+2); mfma m23 x n23
    #pragma unroll
    for (int m = 0; m < 2; ++m)
      #pragma unroll
      for (int k = 0; k < 2; ++k) aHi[m][k] = rdA(cur, wr, m + 2, k, l);
    if (st) stage_chunkB(B, ldb, n0, kt + 2, nxt, w, l);
    __builtin_amdgcn_s_barrier();
    LGKM0;
    __builtin_amdgcn_s_setprio(1);
    #pragma unroll
    for (int m = 0; m < 2; ++m)
      #pragma unroll
      for (int n = 0; n < 2; ++n)
        #pragma unroll
        for (int k = 0; k < 2; ++k)
          acc[m + 2][n + 2] = __builtin_amdgcn_mfma_f32_16x16x32_bf16(aHi[m][k], bHi[n][k], acc[m + 2][n + 2], 0, 0, 0);
    __builtin_amdgcn_s_setprio(0);
    __builtin_amdgcn_s_barrier();
    CFENCE;

    // ---- phase 3: no reads; mfma m23 x n01; once-per-tile counted wait
    __builtin_amdgcn_s_setprio(1);
    #pragma unroll
    for (int m = 0; m < 2; ++m)
      #pragma unroll
      for (int n = 0; n < 2; ++n)
        #pragma unroll
        for (int k = 0; k < 2; ++k)
          acc[m + 2][n] = __builtin_amdgcn_mfma_f32_16x16x32_bf16(aHi[m][k], bLo[n][k], acc[m + 2][n], 0, 0, 0);
    __builtin_amdgcn_s_setprio(0);
    if (st) {
      asm volatile("s_waitcnt vmcnt(6)" ::: "memory");   // tile kt+1 resident, kt+2 in flight
    } else if (kt + 1 < NT) {
      asm volatile("s_waitcnt vmcnt(0)" ::: "memory");   // final drain
    }
    __builtin_amdgcn_s_barrier();
    CFENCE;
  }
}

// ---------------------------------------------------------------------------
// 1) fp32 -> bf16 convert
// ---------------------------------------------------------------------------
__global__ __launch_bounds__(256)
void convert_k(const float* __restrict__ X,
               const float* __restrict__ WQ,
               const float* __restrict__ WK,
               const float* __restrict__ WV,
               u16* __restrict__ Xb, u16* __restrict__ Wb)
{
  const int NX = (BATCH*SEQ*DMODEL) / 4;
  const int NW = (DMODEL*DMODEL) / 4;
  const int total = NX + 3*NW;
  for (int i = blockIdx.x * 256 + threadIdx.x; i < total; i += gridDim.x * 256) {
    const float4* src; u16* dst; int j;
    if (i < NX) { src = (const float4*)X; j = i; dst = Xb; }
    else {
      int t = i - NX; int w = t / NW; j = t - w * NW;
      src = (const float4*)(w == 0 ? WQ : (w == 1 ? WK : WV));
      dst = Wb + (size_t)w * (DMODEL*DMODEL);
    }
    float4 v = src[j];
    ushortx4 p = { f2bf(v.x), f2bf(v.y), f2bf(v.z), f2bf(v.w) };
    *(ushortx4*)(dst + (size_t)j * 4) = p;
  }
}

// ---------------------------------------------------------------------------
// 2) QKV projection, 768 blocks (exactly 3 CU-rounds), XCD-chunked swizzle
// ---------------------------------------------------------------------------
__global__ __launch_bounds__(512, 1)
void qkv8(const u16* __restrict__ Xb, const u16* __restrict__ Wb,
          u16* __restrict__ Q, u16* __restrict__ K, u16* __restrict__ Vt)
{
  __shared__ u16 lds[3*LDSHALF];
  const int id = blockIdx.x;
  const int sw = (id & 7) * 96 + (id >> 3);   // 768 % 8 == 0, bijective
  const int mt = sw / 24, r = sw % 24;
  const int z = r >> 3, nt = r & 7;
  const int m0 = mt * GBM, n0 = nt * GBN;

  floatx4 acc[4][4] = {};
  gemm8_core(Xb, DMODEL, Wb + (size_t)z * DMODEL * DMODEL, DMODEL,
             m0, n0, DMODEL/GBK, lds, acc);

  const int l = threadIdx.x & 63, w = threadIdx.x >> 6;
  const int wr = w >> 1, wc = w & 1;
  const int row0 = m0 + wr*64 + ((l >> 4) << 2);
  const int col0 = n0 + wc*64 + (l & 15);

  if (z < 2) {
    u16* O = z ? K : Q;
    #pragma unroll
    for (int m = 0; m < 4; ++m)
      #pragma unroll
      for (int n = 0; n < 4; ++n)
        #pragma unroll
        for (int i = 0; i < 4; ++i)
          O[(size_t)(row0 + m*16 + i) * DMODEL + col0 + n*16] = f2bf(acc[m][n][i]);
  } else {
    #pragma unroll
    for (int m = 0; m < 4; ++m) {
      int gm = row0 + m*16;
      int b = gm >> 11, s = gm & (SEQ - 1);
      #pragma unroll
      for (int n = 0; n < 4; ++n) {
        int d = col0 + n*16;
        ushortx4 p = { f2bf(acc[m][n][0]), f2bf(acc[m][n][1]),
                       f2bf(acc[m][n][2]), f2bf(acc[m][n][3]) };
        *(ushortx4*)(Vt + ((size_t)b * DMODEL + d) * SEQ + s) = p;
      }
    }
  }
}

// ---------------------------------------------------------------------------
// 3) scores = Q @ K^T / 32, causal 256x128 tiles only (72/batch, 288 blocks)
// ---------------------------------------------------------------------------
__global__ __launch_bounds__(512, 1)
void scores8(const u16* __restrict__ Qb, const u16* __restrict__ Kb,
             float* __restrict__ Sc)
{
  __shared__ u16 lds[3*LDSHALF];
  const int id = blockIdx.x;
  const int sw = (id & 7) * 36 + (id >> 3);   // 288 % 8 == 0
  const int b = sw / 72;
  const int t = sw % 72;
  int qt = 0;
  while ((qt + 1) * (qt + 2) <= t) ++qt;      // cum(qt) = qt*(qt+1)
  const int nt = t - qt * (qt + 1);           // 0 .. 2qt+1
  const int m0 = qt * GBM, n0 = nt * GBN;

  const u16* Q = Qb + (size_t)b * SEQ * DMODEL;
  const u16* K = Kb + (size_t)b * SEQ * DMODEL;
  floatx4 acc[4][4] = {};
  gemm8_core(Q, DMODEL, K, DMODEL, m0, n0, DMODEL/GBK, lds, acc);

  float* S = Sc + (size_t)b * SEQ * SEQ;
  const int l = threadIdx.x & 63, w = threadIdx.x >> 6;
  const int wr = w >> 1, wc = w & 1;
  const int row0 = m0 + wr*64 + ((l >> 4) << 2);
  const int col0 = n0 + wc*64 + (l & 15);
  #pragma unroll
  for (int m = 0; m < 4; ++m)
    #pragma unroll
    for (int n = 0; n < 4; ++n)
      #pragma unroll
      for (int i = 0; i < 4; ++i)
        S[(size_t)(row0 + m*16 + i) * SEQ + col0 + n*16] = acc[m][n][i] * 0.03125f;
}

// ---------------------------------------------------------------------------
// 4) causal row softmax, in-place bf16 P overlay; zero-fill to 256-boundary
// ---------------------------------------------------------------------------
__global__ __launch_bounds__(256)
void softmax_k(float* __restrict__ Sc)
{
  __shared__ float buf[SEQ];
  __shared__ float red[4];
  const int rg = blockIdx.x;
  const int q = rg & (SEQ - 1);
  float* row = Sc + (size_t)rg * SEQ;
  u16* prow = (u16*)row;
  const int tid = threadIdx.x;
  const int lane = tid & 63, wave = tid >> 6;
  const int n = q + 1;
  const int kpad = ((q >> 8) + 1) << 8;   // 256-tile boundary

  float lmax = -3.4e38f;
  for (int k = tid; k < n; k += 256) {
    float v = row[k];
    buf[k] = v;
    lmax = fmaxf(lmax, v);
  }
  #pragma unroll
  for (int off = 32; off >= 1; off >>= 1)
    lmax = fmaxf(lmax, __shfl_xor(lmax, off));
  if (lane == 0) red[wave] = lmax;
  __syncthreads();
  const float rmax = fmaxf(fmaxf(red[0], red[1]), fmaxf(red[2], red[3]));
  __syncthreads();

  float lsum = 0.f;
  for (int k = tid; k < n; k += 256) {
    float e = __expf(buf[k] - rmax);
    buf[k] = e;
    lsum += e;
  }
  #pragma unroll
  for (int off = 32; off >= 1; off >>= 1)
    lsum += __shfl_xor(lsum, off);
  if (lane == 0) red[wave] = lsum;
  __syncthreads();
  const float inv = 1.f / (red[0] + red[1] + red[2] + red[3]);

  for (int k = tid; k < kpad; k += 256) {
    float p = (k < n) ? buf[k] * inv : 0.f;
    prow[k] = f2bf(p);
  }
}

// ---------------------------------------------------------------------------
// 5) O = P @ V, causal K bound; 256 blocks = 1 full CU-round
// ---------------------------------------------------------------------------
__global__ __launch_bounds__(512, 1)
void out8(const float* __restrict__ Sc, const u16* __restrict__ Vt,
          float* __restrict__ Out)
{
  __shared__ u16 lds[3*LDSHALF];
  const int id = blockIdx.x;
  const int qt = id & 7;          // qt varies fastest -> uniform XCD mix
  const int b  = (id >> 3) & 3;
  const int nt = id >> 5;
  const int m0 = qt * GBM, n0 = nt * GBN;

  const u16* P = (const u16*)(Sc + (size_t)b * SEQ * SEQ);  // lda = 2*SEQ u16
  const u16* V = Vt + (size_t)b * DMODEL * SEQ;             // ldb = SEQ
  const int NT = (qt + 1) * (GBM / GBK);

  floatx4 acc[4][4] = {};
  gemm8_core(P, 2*SEQ, V, SEQ, m0, n0, NT, lds, acc);

  float* O = Out + (size_t)b * SEQ * DMODEL;
  const int l = threadIdx.x & 63, w = threadIdx.x >> 6;
  const int wr = w >> 1, wc = w & 1;
  const int row0 = m0 + wr*64 + ((l >> 4) << 2);
  const int col0 = n0 + wc*64 + (l & 15);
  #pragma unroll
  for (int m = 0; m < 4; ++m)
    #pragma unroll
    for (int n = 0; n < 4; ++n)
      #pragma unroll
      for (int i = 0; i < 4; ++i)
        O[(size_t)(row0 + m*16 + i) * DMODEL + col0 + n*16] = acc[m][n][i];
}

// ---------------------------------------------------------------------------
extern "C" void kernel_launch(void* const* d_in, const int* in_sizes, int n_in,
                              void* d_out, int out_size, void* d_ws, size_t ws_size,
                              hipStream_t stream)
{
  const float* X  = (const float*)d_in[0];
  const float* WQ = (const float*)d_in[1];
  const float* WK = (const float*)d_in[2];
  const float* WV = (const float*)d_in[3];
  float* Out = (float*)d_out;

  char* ws = (char*)d_ws;
  u16*   Xb = (u16*)(ws);                       // 16,777,216 B
  u16*   Wb = (u16*)(ws + 16777216);            //  6,291,456 B
  u16*   Qb = (u16*)(ws + 23068672);            // 16,777,216 B
  u16*   Kb = (u16*)(ws + 39845888);            // 16,777,216 B
  u16*   Vt = (u16*)(ws + 56623104);            // 16,777,216 B
  float* Sc = (float*)(ws + 73400320);          // 67,108,864 B

  convert_k<<<dim3(2048), dim3(256), 0, stream>>>(X, WQ, WK, WV, Xb, Wb);
  qkv8<<<dim3(768), dim3(512), 0, stream>>>(Xb, Wb, Qb, Kb, Vt);
  scores8<<<dim3(288), dim3(512), 0, stream>>>(Qb, Kb, Sc);
  softmax_k<<<dim3(BATCH * SEQ), dim3(256), 0, stream>>>(Sc);
  out8<<<dim3(256), dim3(512), 0, stream>>>(Sc, Vt, Out);
}

// Round 5
// 143.621 us; speedup vs baseline: 1.3912x; 1.1641x over previous
//
#include <hip/hip_runtime.h>

typedef unsigned short u16;
typedef __attribute__((ext_vector_type(8))) short short8;
typedef __attribute__((ext_vector_type(4))) float floatx4;
typedef __attribute__((ext_vector_type(4))) unsigned short ushortx4;

#define BATCH 4
#define SEQ   2048
#define DMODEL 1024

__device__ __forceinline__ u16 f2bf(float f) {
  unsigned int u = __builtin_bit_cast(unsigned int, f);
  u = (u + 0x7FFFu + ((u >> 16) & 1u)) >> 16;
  return (u16)u;
}

typedef const __attribute__((address_space(1))) unsigned int as1_u32;
typedef __attribute__((address_space(3))) unsigned int as3_u32;

__device__ __forceinline__ void gload16(const void* gp, void* lp) {
  __builtin_amdgcn_global_load_lds((as1_u32*)gp, (as3_u32*)lp, 16, 0, 0);
}

#define CFENCE asm volatile("" ::: "memory")
#define LGKM0  do { asm volatile("s_waitcnt lgkmcnt(0)" ::: "memory"); \
                    __builtin_amdgcn_sched_barrier(0); } while (0)

// ---------------------------------------------------------------------------
// Staging: one "unit" = half of A or B of one K-tile (BK=64); 2 gloads/thread.
// LDS dest linear (DMA = wave-uniform base + lane*16); XOR swizzle applied on
// the GLOBAL source 16B slot (s ^ row&7); readers XOR the same on the address.
// ---------------------------------------------------------------------------
template<int NW, int STRIPE>
__device__ __forceinline__ void stage_unit(
    const u16* __restrict__ G, int ld, int org, int kt, int h,
    u16* region, int w, int l)
{
  constexpr int CPS = STRIPE / 16;       // chunks per half-stripe
  const int lr = l >> 3, s = l & 7;
  #pragma unroll
  for (int i = 0; i < 2; ++i) {
    int c = i * NW + w;
    int R = (c / CPS) * STRIPE + h * (STRIPE / 2) + (c % CPS) * 8;
    const u16* src = G + (size_t)(org + R + lr) * ld + kt * 64 + ((s ^ lr) << 3);
    gload16(src, region + R * 64);
  }
}

template<int REP>
__device__ __forceinline__ short8 rdfrag(const u16* region, int wq, int m, int kh, int l) {
  int r = wq * (REP * 16) + m * 16 + (l & 15);
  int c = kh * 32 + ((l >> 4) << 3);
  return *(const short8*)(region + ((r * 64 + c) ^ ((r & 7) << 3)));
}

// ---------------------------------------------------------------------------
// Deep-pipelined Bt-form GEMM core, 3 phases per K-tile (BK=64), 2 LDS bufs.
// Per-wave output: (MREP*16) x (NREP*16).  Schedule (region-lifetime proven):
//  Ph0: read aLo(12? MH*2)+bLo; issue B1(t+1),A1(t+1)->other buf; vmcnt(10);
//       lgkm0; barrier; MFMA mLo x nLo
//  Ph1: read bHi; issue A0(t+2)->own buf (aLo region, free after Ph0);
//       vmcnt(10); lgkm0; barrier; MFMA mLo x nHi
//  Ph2: read aHi; issue B0(t+2)->own buf (bLo region, free after Ph0);
//       vmcnt(8);  lgkm0; barrier; MFMA mHi x nHi + mHi x nLo
// Counted vmcnt never drains to 0 in steady state; tail issues are clamped
// dummies so the counts stay uniform.
// ---------------------------------------------------------------------------
template<int WM, int WN, int MREP, int NREP>
__device__ __forceinline__ void gemm_core(
    const u16* __restrict__ A, int lda,
    const u16* __restrict__ B, int ldb,
    int m0, int n0, int NT, u16* lds,
    floatx4 (&acc)[MREP][NREP])
{
  constexpr int NW = WM * WN;
  constexpr int BM = WM * MREP * 16, BN = WN * NREP * 16;
  constexpr int ABUF = BM * 64;          // u16 offset of B region
  constexpr int BUFSZ = (BM + BN) * 64;  // u16 per buffer
  constexpr int MH = MREP / 2, NH = NREP / 2;
  constexpr int SA = BM / WM, SB = BN / WN;

  const int tid = threadIdx.x;
  const int w = tid >> 6, l = tid & 63;
  const int wr = w / WN, wc = w % WN;

  u16* buf0 = lds;
  u16* buf1 = lds + BUFSZ;

  // prologue: A0(0), B0(0), B1(0), A1(0), A0(1), B0(1)  [stream order matters]
  stage_unit<NW, SA>(A, lda, m0, 0, 0, buf0, w, l);
  stage_unit<NW, SB>(B, ldb, n0, 0, 0, buf0 + ABUF, w, l);
  stage_unit<NW, SB>(B, ldb, n0, 0, 1, buf0 + ABUF, w, l);
  stage_unit<NW, SA>(A, lda, m0, 0, 1, buf0, w, l);
  stage_unit<NW, SA>(A, lda, m0, 1, 0, buf1, w, l);
  stage_unit<NW, SB>(B, ldb, n0, 1, 0, buf1 + ABUF, w, l);
  asm volatile("s_waitcnt vmcnt(8)" ::: "memory");
  __builtin_amdgcn_s_barrier();
  CFENCE;

  for (int kt = 0; kt < NT; ++kt) {
    u16* cur = (kt & 1) ? buf1 : buf0;
    u16* oth = (kt & 1) ? buf0 : buf1;
    const int t1 = (kt + 1 < NT) ? kt + 1 : NT - 1;
    const int t2 = (kt + 2 < NT) ? kt + 2 : NT - 1;

    short8 aLo[MH][2], aHi[MH][2], bLo[NH][2], bHi[NH][2];

    // ---- Phase 0 ----
    #pragma unroll
    for (int m = 0; m < MH; ++m)
      #pragma unroll
      for (int k = 0; k < 2; ++k) aLo[m][k] = rdfrag<MREP>(cur, wr, m, k, l);
    #pragma unroll
    for (int n = 0; n < NH; ++n)
      #pragma unroll
      for (int k = 0; k < 2; ++k) bLo[n][k] = rdfrag<NREP>(cur + ABUF, wc, n, k, l);
    stage_unit<NW, SB>(B, ldb, n0, t1, 1, oth + ABUF, w, l);
    stage_unit<NW, SA>(A, lda, m0, t1, 1, oth, w, l);
    asm volatile("s_waitcnt vmcnt(10)" ::: "memory");
    LGKM0;
    __builtin_amdgcn_s_barrier();
    CFENCE;
    __builtin_amdgcn_s_setprio(1);
    #pragma unroll
    for (int m = 0; m < MH; ++m)
      #pragma unroll
      for (int n = 0; n < NH; ++n)
        #pragma unroll
        for (int k = 0; k < 2; ++k)
          acc[m][n] = __builtin_amdgcn_mfma_f32_16x16x32_bf16(aLo[m][k], bLo[n][k], acc[m][n], 0, 0, 0);
    __builtin_amdgcn_s_setprio(0);

    // ---- Phase 1 ----
    #pragma unroll
    for (int n = 0; n < NH; ++n)
      #pragma unroll
      for (int k = 0; k < 2; ++k) bHi[n][k] = rdfrag<NREP>(cur + ABUF, wc, n + NH, k, l);
    stage_unit<NW, SA>(A, lda, m0, t2, 0, cur, w, l);
    asm volatile("s_waitcnt vmcnt(10)" ::: "memory");
    LGKM0;
    __builtin_amdgcn_s_barrier();
    CFENCE;
    __builtin_amdgcn_s_setprio(1);
    #pragma unroll
    for (int m = 0; m < MH; ++m)
      #pragma unroll
      for (int n = 0; n < NH; ++n)
        #pragma unroll
        for (int k = 0; k < 2; ++k)
          acc[m][n + NH] = __builtin_amdgcn_mfma_f32_16x16x32_bf16(aLo[m][k], bHi[n][k], acc[m][n + NH], 0, 0, 0);
    __builtin_amdgcn_s_setprio(0);

    // ---- Phase 2 ----
    #pragma unroll
    for (int m = 0; m < MH; ++m)
      #pragma unroll
      for (int k = 0; k < 2; ++k) aHi[m][k] = rdfrag<MREP>(cur, wr, m + MH, k, l);
    stage_unit<NW, SB>(B, ldb, n0, t2, 0, cur + ABUF, w, l);
    asm volatile("s_waitcnt vmcnt(8)" ::: "memory");
    LGKM0;
    __builtin_amdgcn_s_barrier();
    CFENCE;
    __builtin_amdgcn_s_setprio(1);
    #pragma unroll
    for (int m = 0; m < MH; ++m)
      #pragma unroll
      for (int n = 0; n < NH; ++n)
        #pragma unroll
        for (int k = 0; k < 2; ++k) {
          acc[m + MH][n + NH] = __builtin_amdgcn_mfma_f32_16x16x32_bf16(aHi[m][k], bHi[n][k], acc[m + MH][n + NH], 0, 0, 0);
          acc[m + MH][n] = __builtin_amdgcn_mfma_f32_16x16x32_bf16(aHi[m][k], bLo[n][k], acc[m + MH][n], 0, 0, 0);
        }
    __builtin_amdgcn_s_setprio(0);
  }
  asm volatile("s_waitcnt vmcnt(0)" ::: "memory");  // drain clamped dummies
}

// ---------------------------------------------------------------------------
// 1) fp32 -> bf16 convert
// ---------------------------------------------------------------------------
__global__ __launch_bounds__(256)
void convert_k(const float* __restrict__ X,
               const float* __restrict__ WQ,
               const float* __restrict__ WK,
               const float* __restrict__ WV,
               u16* __restrict__ Xb, u16* __restrict__ Wb)
{
  const int NX = (BATCH*SEQ*DMODEL) / 4;
  const int NW_ = (DMODEL*DMODEL) / 4;
  const int total = NX + 3*NW_;
  for (int i = blockIdx.x * 256 + threadIdx.x; i < total; i += gridDim.x * 256) {
    const float4* src; u16* dst; int j;
    if (i < NX) { src = (const float4*)X; j = i; dst = Xb; }
    else {
      int t = i - NX; int w = t / NW_; j = t - w * NW_;
      src = (const float4*)(w == 0 ? WQ : (w == 1 ? WK : WV));
      dst = Wb + (size_t)w * (DMODEL*DMODEL);
    }
    float4 v = src[j];
    ushortx4 p = { f2bf(v.x), f2bf(v.y), f2bf(v.z), f2bf(v.w) };
    *(ushortx4*)(dst + (size_t)j * 4) = p;
  }
}

// ---------------------------------------------------------------------------
// 2a) Q,K projection: 256x256 tiles, 8 waves, 256 blocks = 1 full CU round
// ---------------------------------------------------------------------------
__global__ __launch_bounds__(512, 2)
void qk256(const u16* __restrict__ Xb, const u16* __restrict__ Wb,
           u16* __restrict__ Q, u16* __restrict__ K)
{
  __shared__ __align__(16) u16 lds[2 * (256 + 256) * 64];
  const int id = blockIdx.x;
  const int sw = (id & 7) * 32 + (id >> 3);    // 256 % 8 == 0, bijective
  const int z = sw >> 7;                       // 0=Q, 1=K
  const int rem = sw & 127;
  const int mt = rem >> 2, nt = rem & 3;
  const int m0 = mt * 256, n0 = nt * 256;

  floatx4 acc[8][4] = {};
  gemm_core<2, 4, 8, 4>(Xb, DMODEL, Wb + (size_t)z * DMODEL * DMODEL, DMODEL,
                        m0, n0, DMODEL / 64, lds, acc);

  const int l = threadIdx.x & 63, w = threadIdx.x >> 6;
  const int wr = w >> 2, wc = w & 3;
  const int row0 = m0 + wr * 128 + ((l >> 4) << 2);
  const int col0 = n0 + wc * 64 + (l & 15);
  u16* O = z ? K : Q;
  #pragma unroll
  for (int m = 0; m < 8; ++m)
    #pragma unroll
    for (int n = 0; n < 4; ++n)
      #pragma unroll
      for (int i = 0; i < 4; ++i)
        O[(size_t)(row0 + m*16 + i) * DMODEL + col0 + n*16] = f2bf(acc[m][n][i]);
}

// ---------------------------------------------------------------------------
// 2b) V projection: 128x128 tiles, 4 waves, 512 blocks (2/CU), transposed out
// ---------------------------------------------------------------------------
__global__ __launch_bounds__(256, 2)
void v128(const u16* __restrict__ Xb, const u16* __restrict__ Wb,
          u16* __restrict__ Vt)
{
  __shared__ __align__(16) u16 lds[2 * (128 + 128) * 64];
  const int id = blockIdx.x;
  const int sw = (id & 7) * 64 + (id >> 3);    // 512 % 8 == 0
  const int mt = sw >> 3, nt = sw & 7;
  const int m0 = mt * 128, n0 = nt * 128;

  floatx4 acc[4][4] = {};
  gemm_core<2, 2, 4, 4>(Xb, DMODEL, Wb + (size_t)2 * DMODEL * DMODEL, DMODEL,
                        m0, n0, DMODEL / 64, lds, acc);

  const int l = threadIdx.x & 63, w = threadIdx.x >> 6;
  const int wr = w >> 1, wc = w & 1;
  const int row0 = m0 + wr * 64 + ((l >> 4) << 2);
  const int col0 = n0 + wc * 64 + (l & 15);
  #pragma unroll
  for (int m = 0; m < 4; ++m) {
    int gm = row0 + m*16;
    int b = gm >> 11, s = gm & (SEQ - 1);
    #pragma unroll
    for (int n = 0; n < 4; ++n) {
      int d = col0 + n*16;
      ushortx4 p = { f2bf(acc[m][n][0]), f2bf(acc[m][n][1]),
                     f2bf(acc[m][n][2]), f2bf(acc[m][n][3]) };
      *(ushortx4*)(Vt + ((size_t)b * DMODEL + d) * SEQ + s) = p;
    }
  }
}

// ---------------------------------------------------------------------------
// 3) scores = Q @ K^T / 32: 128x128 causal tiles (136/batch, 544 blocks)
// ---------------------------------------------------------------------------
__global__ __launch_bounds__(256, 2)
void scores128(const u16* __restrict__ Qb, const u16* __restrict__ Kb,
               float* __restrict__ Sc)
{
  __shared__ __align__(16) u16 lds[2 * (128 + 128) * 64];
  const int id = blockIdx.x;
  const int sw = (id & 7) * 68 + (id >> 3);    // 544 % 8 == 0
  const int b = sw / 136;
  const int t = sw % 136;
  int qt = 0;
  while ((qt + 1) * (qt + 2) / 2 <= t) ++qt;
  const int kt = t - qt * (qt + 1) / 2;
  const int m0 = qt * 128, n0 = kt * 128;

  const u16* Q = Qb + (size_t)b * SEQ * DMODEL;
  const u16* K = Kb + (size_t)b * SEQ * DMODEL;
  floatx4 acc[4][4] = {};
  gemm_core<2, 2, 4, 4>(Q, DMODEL, K, DMODEL, m0, n0, DMODEL / 64, lds, acc);

  float* S = Sc + (size_t)b * SEQ * SEQ;
  const int l = threadIdx.x & 63, w = threadIdx.x >> 6;
  const int wr = w >> 1, wc = w & 1;
  const int row0 = m0 + wr * 64 + ((l >> 4) << 2);
  const int col0 = n0 + wc * 64 + (l & 15);
  #pragma unroll
  for (int m = 0; m < 4; ++m)
    #pragma unroll
    for (int n = 0; n < 4; ++n)
      #pragma unroll
      for (int i = 0; i < 4; ++i)
        S[(size_t)(row0 + m*16 + i) * SEQ + col0 + n*16] = acc[m][n][i] * 0.03125f;
}

// ---------------------------------------------------------------------------
// 4) causal row softmax, in-place bf16 P overlay; zero-fill to 256-boundary
// ---------------------------------------------------------------------------
__global__ __launch_bounds__(256)
void softmax_k(float* __restrict__ Sc)
{
  __shared__ float buf[SEQ];
  __shared__ float red[4];
  const int rg = blockIdx.x;
  const int q = rg & (SEQ - 1);
  float* row = Sc + (size_t)rg * SEQ;
  u16* prow = (u16*)row;
  const int tid = threadIdx.x;
  const int lane = tid & 63, wave = tid >> 6;
  const int n = q + 1;
  const int kpad = ((q >> 8) + 1) << 8;

  float lmax = -3.4e38f;
  for (int k = tid; k < n; k += 256) {
    float v = row[k];
    buf[k] = v;
    lmax = fmaxf(lmax, v);
  }
  #pragma unroll
  for (int off = 32; off >= 1; off >>= 1)
    lmax = fmaxf(lmax, __shfl_xor(lmax, off));
  if (lane == 0) red[wave] = lmax;
  __syncthreads();
  const float rmax = fmaxf(fmaxf(red[0], red[1]), fmaxf(red[2], red[3]));
  __syncthreads();

  float lsum = 0.f;
  for (int k = tid; k < n; k += 256) {
    float e = __expf(buf[k] - rmax);
    buf[k] = e;
    lsum += e;
  }
  #pragma unroll
  for (int off = 32; off >= 1; off >>= 1)
    lsum += __shfl_xor(lsum, off);
  if (lane == 0) red[wave] = lsum;
  __syncthreads();
  const float inv = 1.f / (red[0] + red[1] + red[2] + red[3]);

  for (int k = tid; k < kpad; k += 256) {
    float p = (k < n) ? buf[k] * inv : 0.f;
    prow[k] = f2bf(p);
  }
}

// ---------------------------------------------------------------------------
// 5) O = P @ V: 128x128 tiles, 512 blocks, complement-qt pairing for balance
// ---------------------------------------------------------------------------
__global__ __launch_bounds__(256, 2)
void out128(const float* __restrict__ Sc, const u16* __restrict__ Vt,
            float* __restrict__ Out)
{
  __shared__ __align__(16) u16 lds[2 * (128 + 128) * 64];
  const int id = blockIdx.x;
  const int j = id & 255;
  const int upper = id >> 8;
  const int qt = upper ? (15 - (j & 15)) : (j & 15);
  const int nt = (j >> 4) & 7;
  const int b  = (upper << 1) | (j >> 7);
  const int m0 = qt * 128, n0 = nt * 128;

  const u16* P = (const u16*)(Sc + (size_t)b * SEQ * SEQ);  // lda = 4096 u16
  const u16* V = Vt + (size_t)b * DMODEL * SEQ;             // ldb = 2048
  const int NT = (qt + 1) * 2;

  floatx4 acc[4][4] = {};
  gemm_core<2, 2, 4, 4>(P, 2 * SEQ, V, SEQ, m0, n0, NT, lds, acc);

  float* O = Out + (size_t)b * SEQ * DMODEL;
  const int l = threadIdx.x & 63, w = threadIdx.x >> 6;
  const int wr = w >> 1, wc = w & 1;
  const int row0 = m0 + wr * 64 + ((l >> 4) << 2);
  const int col0 = n0 + wc * 64 + (l & 15);
  #pragma unroll
  for (int m = 0; m < 4; ++m)
    #pragma unroll
    for (int n = 0; n < 4; ++n)
      #pragma unroll
      for (int i = 0; i < 4; ++i)
        O[(size_t)(row0 + m*16 + i) * DMODEL + col0 + n*16] = acc[m][n][i];
}

// ---------------------------------------------------------------------------
extern "C" void kernel_launch(void* const* d_in, const int* in_sizes, int n_in,
                              void* d_out, int out_size, void* d_ws, size_t ws_size,
                              hipStream_t stream)
{
  const float* X  = (const float*)d_in[0];
  const float* WQ = (const float*)d_in[1];
  const float* WK = (const float*)d_in[2];
  const float* WV = (const float*)d_in[3];
  float* Out = (float*)d_out;

  char* ws = (char*)d_ws;
  u16*   Xb = (u16*)(ws);                       // 16,777,216 B
  u16*   Wb = (u16*)(ws + 16777216);            //  6,291,456 B
  u16*   Qb = (u16*)(ws + 23068672);            // 16,777,216 B
  u16*   Kb = (u16*)(ws + 39845888);            // 16,777,216 B
  u16*   Vt = (u16*)(ws + 56623104);            // 16,777,216 B
  float* Sc = (float*)(ws + 73400320);          // 67,108,864 B

  convert_k<<<dim3(2048), dim3(256), 0, stream>>>(X, WQ, WK, WV, Xb, Wb);
  qk256<<<dim3(256), dim3(512), 0, stream>>>(Xb, Wb, Qb, Kb);
  v128<<<dim3(512), dim3(256), 0, stream>>>(Xb, Wb, Vt);
  scores128<<<dim3(544), dim3(256), 0, stream>>>(Qb, Kb, Sc);
  softmax_k<<<dim3(BATCH * SEQ), dim3(256), 0, stream>>>(Sc);
  out128<<<dim3(512), dim3(256), 0, stream>>>(Sc, Vt, Out);
}